// Round 11
// baseline (764.486 us; speedup 1.0000x reference)
//
#include <hip/hip_runtime.h>

// SNG: sn[b,l] = 8-step majority chain (reference scan unrolled):
//   v_0 = 0; v_{i+1} = maj(x[b,i], v_i, r[b,i,l+i]); sn[b,l] = v_8
// maj(1,v,r) = v|r ; maj(0,v,r) = v&r.
//
// v9 (re-run; round-10 bench lost to GPUAcquisitionTimeout):
// v8 (best, 669.1) launched TWICE — measurement round. dur_us - 669
// isolates the kernel's own duration from the ~515-585us of fixed harness
// stream traffic (ws poison fill + input restore) that dominates dur_us.
// Idempotent: both launches write identical output.

#define BATCH 1024
#define PBITS 8
#define LBITS 16384
#define TLEN (PBITS + LBITS)   // 16392 dwords per r-row

typedef int v4i __attribute__((ext_vector_type(4)));

__global__ __launch_bounds__(256) void sng_kernel(const int* __restrict__ num,
                                                  const int* __restrict__ r,
                                                  int* __restrict__ out) {
    const int t = threadIdx.x;                 // 0..255
    const int b = blockIdx.x >> 2;             // 4 blocks per batch row
    const int jb = (blockIdx.x & 3) << 12;     // dword base within row

    const int nb = num[b];                     // wave-uniform -> SGPR
    const int start = __builtin_ctz(nb | 256); // first relevant row (8 if nb==0)

    const int* rb = r + (size_t)b * (PBITS * TLEN) + jb + (t << 2);

    v4i v0 = {0,0,0,0}, v1 = {0,0,0,0}, v2 = {0,0,0,0}, v3 = {0,0,0,0};

#pragma unroll
    for (int i = 0; i < PBITS; ++i) {
        if (i < start) continue;               // block-uniform scalar skip
        const int* rp = rb + i * TLEN + i;     // diagonal shift +i
        const v4i a0 = __builtin_nontemporal_load(reinterpret_cast<const v4i*>(rp));
        const v4i a1 = __builtin_nontemporal_load(reinterpret_cast<const v4i*>(rp + 1024));
        const v4i a2 = __builtin_nontemporal_load(reinterpret_cast<const v4i*>(rp + 2048));
        const v4i a3 = __builtin_nontemporal_load(reinterpret_cast<const v4i*>(rp + 3072));
        if ((nb >> i) & 1) {                   // block-uniform: OR row
            v0 |= a0; v1 |= a1; v2 |= a2; v3 |= a3;
        } else {                               // AND row
            v0 &= a0; v1 &= a1; v2 &= a2; v3 &= a3;
        }
    }

    v4i* o = reinterpret_cast<v4i*>(out) + ((blockIdx.x << 10) | t);
    __builtin_nontemporal_store(v0, o);
    __builtin_nontemporal_store(v1, o + 256);
    __builtin_nontemporal_store(v2, o + 512);
    __builtin_nontemporal_store(v3, o + 768);
}

extern "C" void kernel_launch(void* const* d_in, const int* in_sizes, int n_in,
                              void* d_out, int out_size, void* d_ws, size_t ws_size,
                              hipStream_t stream) {
    const int* num = (const int*)d_in[0];   // [B] int32
    const int* r   = (const int*)d_in[1];   // [B, P, P+L] int32 (0/1)
    int* out = (int*)d_out;                 // [B, L] int32 (0/1)

    const int blocks = BATCH * 4;           // 4096 blocks x 256 thr, 16 out/thread
    // Launched twice (identical, idempotent): dur_us - single-launch baseline
    // = kernel's own duration. See decision rule in round-10 analysis.
    sng_kernel<<<blocks, 256, 0, stream>>>(num, r, out);
    sng_kernel<<<blocks, 256, 0, stream>>>(num, r, out);
}

// Round 12
// 665.387 us; speedup vs baseline: 1.1489x; 1.1489x over previous
//
#include <hip/hip_runtime.h>

// SNG: sn[b,l] = 8-step majority chain (reference scan unrolled):
//   v_0 = 0; v_{i+1} = maj(x[b,i], v_i, r[b,i,l+i]); sn[b,l] = v_8
// maj(1,v,r) = v|r ; maj(0,v,r) = v&r.
//
// v12 = v8 restored (single launch; v9/v11 was the 2x-launch measurement).
// Measured kernel duration: 95.4 us (764.5 - 669.1) for ~537 MB of traffic
// = 5.63 TB/s = 88-89% of this box's pure-fill BW (6.35-6.45 TB/s) -> at the
// practical HBM roofline for a mixed 8-stream read + 1-stream write pattern.
//  - leading-row skip: rows i < ctz(nb) leave v=0 -> loads skipped (block-
//    uniform scalar branch, ~12.5% read savings)
//  - uniform-branch combine: single v_or/v_and per element (nb block-uniform)
//  - per-instruction lane-contiguous nt loads/stores (v5 proved de-coalescing
//    costs 4x request amplification; v7 proved LDS re-alignment costs more
//    than the 4B-misaligned direct streams)

#define BATCH 1024
#define PBITS 8
#define LBITS 16384
#define TLEN (PBITS + LBITS)   // 16392 dwords per r-row

typedef int v4i __attribute__((ext_vector_type(4)));

__global__ __launch_bounds__(256) void sng_kernel(const int* __restrict__ num,
                                                  const int* __restrict__ r,
                                                  int* __restrict__ out) {
    const int t = threadIdx.x;                 // 0..255
    const int b = blockIdx.x >> 2;             // 4 blocks per batch row
    const int jb = (blockIdx.x & 3) << 12;     // dword base within row

    const int nb = num[b];                     // wave-uniform -> SGPR
    const int start = __builtin_ctz(nb | 256); // first relevant row (8 if nb==0)

    const int* rb = r + (size_t)b * (PBITS * TLEN) + jb + (t << 2);

    v4i v0 = {0,0,0,0}, v1 = {0,0,0,0}, v2 = {0,0,0,0}, v3 = {0,0,0,0};

#pragma unroll
    for (int i = 0; i < PBITS; ++i) {
        if (i < start) continue;               // block-uniform scalar skip
        const int* rp = rb + i * TLEN + i;     // diagonal shift +i
        const v4i a0 = __builtin_nontemporal_load(reinterpret_cast<const v4i*>(rp));
        const v4i a1 = __builtin_nontemporal_load(reinterpret_cast<const v4i*>(rp + 1024));
        const v4i a2 = __builtin_nontemporal_load(reinterpret_cast<const v4i*>(rp + 2048));
        const v4i a3 = __builtin_nontemporal_load(reinterpret_cast<const v4i*>(rp + 3072));
        if ((nb >> i) & 1) {                   // block-uniform: OR row
            v0 |= a0; v1 |= a1; v2 |= a2; v3 |= a3;
        } else {                               // AND row
            v0 &= a0; v1 &= a1; v2 &= a2; v3 &= a3;
        }
    }

    v4i* o = reinterpret_cast<v4i*>(out) + ((blockIdx.x << 10) | t);
    __builtin_nontemporal_store(v0, o);
    __builtin_nontemporal_store(v1, o + 256);
    __builtin_nontemporal_store(v2, o + 512);
    __builtin_nontemporal_store(v3, o + 768);
}

extern "C" void kernel_launch(void* const* d_in, const int* in_sizes, int n_in,
                              void* d_out, int out_size, void* d_ws, size_t ws_size,
                              hipStream_t stream) {
    const int* num = (const int*)d_in[0];   // [B] int32
    const int* r   = (const int*)d_in[1];   // [B, P, P+L] int32 (0/1)
    int* out = (int*)d_out;                 // [B, L] int32 (0/1)

    const int blocks = BATCH * 4;           // 4096 blocks x 256 thr, 16 out/thread
    sng_kernel<<<blocks, 256, 0, stream>>>(num, r, out);
}